// Round 8
// baseline (56.308 us; speedup 1.0000x reference)
//
#include <hip/hip_runtime.h>
#include <hip/hip_fp16.h>

#define KN    4096
#define LTOT  6
#define BATCH 8192
#define ROWS  8
#define NT    1024
#define NITER (KN / NT)          // 4
#define NBLK  (BATCH / ROWS)     // 1024
#define NWAVE (NT / 64)          // 16

#if __has_builtin(__builtin_amdgcn_cvt_pk_u8_f32)
#define CVT_PK_U8(o, r, enc) __builtin_amdgcn_cvt_pk_u8_f32((o), (r), (enc))
#else
#define CVT_PK_U8(o, r, enc) ((enc) | ((unsigned)(int)(o) << (8 * (r))))
#endif

// Packed operand record, 12 B/neuron:
//   x = (ia*8) | ((ib*8) << 16)   -- pre-scaled LDS byte offsets (uint2 slots)
//   y = half2(255*c1 + 0.5, ca)   -- u8 scale + rounding bias folded into c1
//   z = half2(cb, cab/255)
__global__ __launch_bounds__(256) void pack_kernel(const float* __restrict__ w0,
                                                   const float* __restrict__ ws,
                                                   const int* __restrict__ idx0,
                                                   const int* __restrict__ idxs,
                                                   uint3* __restrict__ pk) {
    const float TAB[16][4] = {
        {0.f, 0.f, 0.f, 0.f}, {0.f, 0.f, 0.f, 1.f}, {0.f, 1.f, 0.f,-1.f}, {0.f, 1.f, 0.f, 0.f},
        {0.f, 0.f, 1.f,-1.f}, {0.f, 0.f, 1.f, 0.f}, {0.f, 1.f, 1.f,-2.f}, {0.f, 1.f, 1.f,-1.f},
        {1.f,-1.f,-1.f, 1.f}, {1.f,-1.f,-1.f, 2.f}, {1.f, 0.f,-1.f, 0.f}, {1.f, 0.f,-1.f, 1.f},
        {1.f,-1.f, 0.f, 0.f}, {1.f,-1.f, 0.f, 1.f}, {1.f, 0.f, 0.f,-1.f}, {1.f, 0.f, 0.f, 0.f}
    };
    int gid = blockIdx.x * 256 + threadIdx.x;
    if (gid >= LTOT * KN) return;
    int l = gid >> 12;
    int k = gid & (KN - 1);
    const float* w = (l == 0) ? (w0 + k * 16) : (ws + ((size_t)((l - 1) * KN + k) << 4));
    float wv[16];
    float m = -1e30f;
#pragma unroll
    for (int j = 0; j < 16; ++j) { wv[j] = w[j]; m = fmaxf(m, wv[j]); }
    float s = 0.f;
#pragma unroll
    for (int j = 0; j < 16; ++j) { wv[j] = __expf(wv[j] - m); s += wv[j]; }
    float inv = 1.0f / s;
    float c0 = 0.f, c1 = 0.f, c2 = 0.f, c3 = 0.f;
#pragma unroll
    for (int j = 0; j < 16; ++j) {
        c0 += wv[j] * TAB[j][0];
        c1 += wv[j] * TAB[j][1];
        c2 += wv[j] * TAB[j][2];
        c3 += wv[j] * TAB[j][3];
    }
    c0 *= inv; c1 *= inv; c2 *= inv; c3 *= inv;

    __half2 y = __floats2half2_rn(255.0f * c0 + 0.5f, c1);
    __half2 z = __floats2half2_rn(c2, c3 * (1.0f / 255.0f));

    int ia, ib;
    if (l == 0) { ia = idx0[k];                            ib = idx0[KN + k]; }
    else        { ia = idxs[(size_t)(l - 1) * 2 * KN + k]; ib = idxs[(size_t)(l - 1) * 2 * KN + KN + k]; }

    uint3 e;
    e.x = ((unsigned)ia * 8u) | (((unsigned)ib * 8u) << 16);
    e.y = *(const unsigned*)&y;
    e.z = *(const unsigned*)&z;
    pk[gid] = e;
}

// One block = 8 batch rows packed as 8x u8 per neuron (uint2) in LDS.
// hbuf = 2 x 32 KB -> 2 blocks/CU x 16 waves = 32 waves/CU.
__global__ __launch_bounds__(NT, 8) void fused_kernel(const float* __restrict__ x,
                                                      const uint3* __restrict__ pk,
                                                      float* __restrict__ out) {
    __shared__ uint2 hbuf[2][KN];        // 64 KB
    __shared__ float red[NWAVE][16];     // 1 KB

    const int t  = threadIdx.x;
    const int b0 = blockIdx.x * ROWS;

    // Features as 0/255 floats per row.
    float f0[ROWS], f1[ROWS];
#pragma unroll
    for (int r = 0; r < ROWS; ++r) {
        f0[r] = x[(size_t)(b0 + r) * 2 + 0] > 0.f ? 255.f : 0.f;
        f1[r] = x[(size_t)(b0 + r) * 2 + 1] > 0.f ? 255.f : 0.f;
    }

    // ---- Layer 0: 2 -> K, writes hbuf[0] ----
#pragma unroll
    for (int i = 0; i < NITER; ++i) {
        int k = t + i * NT;
        uint3 e = pk[k];
        float2 cA = __half22float2(*(const __half2*)&e.y);   // (c1'', ca)
        float2 cB = __half22float2(*(const __half2*)&e.z);   // (cb, cab')
        unsigned enc0 = 0, enc1 = 0;
#pragma unroll
        for (int r = 0; r < 4; ++r) {
            float A0 = (e.x & 0xffffu) ? f1[r]     : f0[r];
            float B0 = (e.x >> 16)     ? f1[r]     : f0[r];
            float A1 = (e.x & 0xffffu) ? f1[r + 4] : f0[r + 4];
            float B1 = (e.x >> 16)     ? f1[r + 4] : f0[r + 4];
            float o0 = fmaf(fmaf(cB.y, B0, cA.y), A0, fmaf(cB.x, B0, cA.x));
            float o1 = fmaf(fmaf(cB.y, B1, cA.y), A1, fmaf(cB.x, B1, cA.x));
            enc0 = CVT_PK_U8(o0, r, enc0);
            enc1 = CVT_PK_U8(o1, r, enc1);
        }
        hbuf[0][k] = make_uint2(enc0, enc1);
    }
    __syncthreads();

    // ---- Layers 1..4: K -> K, ping-pong ----
#pragma unroll
    for (int l = 1; l <= 4; ++l) {
        const uint3* __restrict__ pl = pk + (size_t)l * KN;
        const char* hs = (const char*)&hbuf[(l + 1) & 1][0];
        uint2*      hd = &hbuf[l & 1][0];
#pragma unroll
        for (int i = 0; i < NITER; ++i) {
            int k = t + i * NT;
            uint3 e = pl[k];
            uint2 av = *(const uint2*)(hs + (e.x & 0xffffu));
            uint2 bv = *(const uint2*)(hs + (e.x >> 16));
            float2 cA = __half22float2(*(const __half2*)&e.y);
            float2 cB = __half22float2(*(const __half2*)&e.z);
            unsigned enc0 = 0, enc1 = 0;
#pragma unroll
            for (int r = 0; r < 4; ++r) {
                float A0 = (float)((av.x >> (8 * r)) & 0xffu);
                float B0 = (float)((bv.x >> (8 * r)) & 0xffu);
                float A1 = (float)((av.y >> (8 * r)) & 0xffu);
                float B1 = (float)((bv.y >> (8 * r)) & 0xffu);
                float o0 = fmaf(fmaf(cB.y, B0, cA.y), A0, fmaf(cB.x, B0, cA.x));
                float o1 = fmaf(fmaf(cB.y, B1, cA.y), A1, fmaf(cB.x, B1, cA.x));
                enc0 = CVT_PK_U8(o0, r, enc0);
                enc1 = CVT_PK_U8(o1, r, enc1);
            }
            hd[k] = make_uint2(enc0, enc1);
        }
        __syncthreads();
    }

    // ---- Layer 5 fused with GroupSum (reads hbuf[0], no quantize/write) ----
    float acc[16];   // [class*8 + row], values are 255*f + 0.5
#pragma unroll
    for (int j = 0; j < 16; ++j) acc[j] = 0.f;
    {
        const uint3* __restrict__ p5 = pk + (size_t)5 * KN;
        const char* hs = (const char*)&hbuf[0][0];
#pragma unroll
        for (int i = 0; i < NITER; ++i) {
            int k = t + i * NT;
            uint3 e = p5[k];
            uint2 av = *(const uint2*)(hs + (e.x & 0xffffu));
            uint2 bv = *(const uint2*)(hs + (e.x >> 16));
            float2 cA = __half22float2(*(const __half2*)&e.y);
            float2 cB = __half22float2(*(const __half2*)&e.z);
            const int cbase = (i >= 2) ? 8 : 0;   // k = t + i*1024; class 1 at k>=2048
#pragma unroll
            for (int r = 0; r < 4; ++r) {
                float A0 = (float)((av.x >> (8 * r)) & 0xffu);
                float B0 = (float)((bv.x >> (8 * r)) & 0xffu);
                float A1 = (float)((av.y >> (8 * r)) & 0xffu);
                float B1 = (float)((bv.y >> (8 * r)) & 0xffu);
                acc[cbase + r]     += fmaf(fmaf(cB.y, B0, cA.y), A0, fmaf(cB.x, B0, cA.x));
                acc[cbase + r + 4] += fmaf(fmaf(cB.y, B1, cA.y), A1, fmaf(cB.x, B1, cA.x));
            }
        }
    }
#pragma unroll
    for (int j = 0; j < 16; ++j)
#pragma unroll
        for (int off = 32; off > 0; off >>= 1)
            acc[j] += __shfl_down(acc[j], off);
    int wave = t >> 6, lane = t & 63;
    if (lane == 0) {
#pragma unroll
        for (int j = 0; j < 16; ++j) red[wave][j] = acc[j];
    }
    __syncthreads();
    if (t < 16) {
        float s = 0.f;
#pragma unroll
        for (int w = 0; w < NWAVE; ++w) s += red[w][t];
        // Each class-sum accumulated 2048 terms of (255*f + 0.5).
        s = (s - 1024.0f) * (1.0f / 255.0f);
        int cls = t >> 3, row = t & 7;
        out[(size_t)(b0 + row) * 2 + cls] = s;
    }
}

extern "C" void kernel_launch(void* const* d_in, const int* in_sizes, int n_in,
                              void* d_out, int out_size, void* d_ws, size_t ws_size,
                              hipStream_t stream) {
    const float* x    = (const float*)d_in[0];
    const float* w0   = (const float*)d_in[1];
    const float* ws   = (const float*)d_in[2];
    const int*   idx0 = (const int*)d_in[3];
    const int*   idxs = (const int*)d_in[4];
    float*       out  = (float*)d_out;
    uint3*       pk   = (uint3*)d_ws;    // LTOT*KN*12 B = 288 KB scratch

    pack_kernel<<<(LTOT * KN + 255) / 256, 256, 0, stream>>>(w0, ws, idx0, idxs, pk);
    fused_kernel<<<NBLK, NT, 0, stream>>>(x, pk, out);
}

// Round 9
// 19.624 us; speedup vs baseline: 2.8693x; 2.8693x over previous
//
#include <hip/hip_runtime.h>

#define KN    4096
#define LTOT  6
#define BATCH 8192
#define NT    1024
#define NITER (KN / NT)          // 4
#define NPAT  4

// Per-neuron operands:
//   pidx[l*KN+k]  = (ia*4) | ((ib*4) << 16)   -- byte offsets into float LDS buffer
//   pcoef[l*KN+k] = {c1, ca, cb, cab} fp32
__global__ __launch_bounds__(256) void pack_kernel(const float* __restrict__ w0,
                                                   const float* __restrict__ ws,
                                                   const int* __restrict__ idx0,
                                                   const int* __restrict__ idxs,
                                                   unsigned* __restrict__ pidx,
                                                   float4* __restrict__ pcoef) {
    const float TAB[16][4] = {
        {0.f, 0.f, 0.f, 0.f}, {0.f, 0.f, 0.f, 1.f}, {0.f, 1.f, 0.f,-1.f}, {0.f, 1.f, 0.f, 0.f},
        {0.f, 0.f, 1.f,-1.f}, {0.f, 0.f, 1.f, 0.f}, {0.f, 1.f, 1.f,-2.f}, {0.f, 1.f, 1.f,-1.f},
        {1.f,-1.f,-1.f, 1.f}, {1.f,-1.f,-1.f, 2.f}, {1.f, 0.f,-1.f, 0.f}, {1.f, 0.f,-1.f, 1.f},
        {1.f,-1.f, 0.f, 0.f}, {1.f,-1.f, 0.f, 1.f}, {1.f, 0.f, 0.f,-1.f}, {1.f, 0.f, 0.f, 0.f}
    };
    int gid = blockIdx.x * 256 + threadIdx.x;
    if (gid >= LTOT * KN) return;
    int l = gid >> 12;
    int k = gid & (KN - 1);
    const float* w = (l == 0) ? (w0 + k * 16) : (ws + ((size_t)((l - 1) * KN + k) << 4));
    float wv[16];
    float m = -1e30f;
#pragma unroll
    for (int j = 0; j < 16; ++j) { wv[j] = w[j]; m = fmaxf(m, wv[j]); }
    float s = 0.f;
#pragma unroll
    for (int j = 0; j < 16; ++j) { wv[j] = __expf(wv[j] - m); s += wv[j]; }
    float inv = 1.0f / s;
    float c0 = 0.f, c1 = 0.f, c2 = 0.f, c3 = 0.f;
#pragma unroll
    for (int j = 0; j < 16; ++j) {
        c0 += wv[j] * TAB[j][0];
        c1 += wv[j] * TAB[j][1];
        c2 += wv[j] * TAB[j][2];
        c3 += wv[j] * TAB[j][3];
    }
    pcoef[gid] = make_float4(c0 * inv, c1 * inv, c2 * inv, c3 * inv);

    int ia, ib;
    if (l == 0) { ia = idx0[k];                            ib = idx0[KN + k]; }
    else        { ia = idxs[(size_t)(l - 1) * 2 * KN + k]; ib = idxs[(size_t)(l - 1) * 2 * KN + KN + k]; }
    pidx[gid] = ((unsigned)ia * 4u) | (((unsigned)ib * 4u) << 16);
}

// One block per input pattern p in {0..3}: f0 = p&1, f1 = (p>>1)&1.
// Full fp32 network eval in LDS; writes table[p*2 + cls].
__global__ __launch_bounds__(NT) void net_kernel(const unsigned* __restrict__ pidx,
                                                 const float4* __restrict__ pcoef,
                                                 float* __restrict__ table) {
    __shared__ float hbuf[2][KN];        // 32 KB
    __shared__ float red[NT / 64][2];

    const int t = threadIdx.x;
    const int p = blockIdx.x;
    const float f0 = (p & 1) ? 1.f : 0.f;
    const float f1 = (p & 2) ? 1.f : 0.f;

    // Layer 0: 2 -> K
#pragma unroll
    for (int i = 0; i < NITER; ++i) {
        int k = t + i * NT;
        unsigned px = pidx[k];
        float4   c  = pcoef[k];
        float A = (px & 0xffffu) ? f1 : f0;
        float B = (px >> 16)     ? f1 : f0;
        hbuf[0][k] = fmaf(fmaf(c.w, B, c.y), A, fmaf(c.z, B, c.x));
    }
    __syncthreads();

    // Layers 1..5: K -> K, ping-pong
#pragma unroll
    for (int l = 1; l < LTOT; ++l) {
        const unsigned* __restrict__ pi = pidx  + (size_t)l * KN;
        const float4*   __restrict__ pc = pcoef + (size_t)l * KN;
        const char* hs = (const char*)&hbuf[(l + 1) & 1][0];
        float*      hd = &hbuf[l & 1][0];
#pragma unroll
        for (int i = 0; i < NITER; ++i) {
            int k = t + i * NT;
            unsigned px = pi[k];
            float4   c  = pc[k];
            float A = *(const float*)(hs + (px & 0xffffu));
            float B = *(const float*)(hs + (px >> 16));
            hd[k] = fmaf(fmaf(c.w, B, c.y), A, fmaf(c.z, B, c.x));
        }
        __syncthreads();
    }

    // GroupSum: final activations in hbuf[1] (layer 5 writes hbuf[5&1]).
    float acc0 = 0.f, acc1 = 0.f;
#pragma unroll
    for (int i = 0; i < NITER; ++i) {
        int k = t + i * NT;
        float v = hbuf[1][k];
        if (k < KN / 2) acc0 += v; else acc1 += v;
    }
#pragma unroll
    for (int off = 32; off > 0; off >>= 1) {
        acc0 += __shfl_down(acc0, off);
        acc1 += __shfl_down(acc1, off);
    }
    int wave = t >> 6, lane = t & 63;
    if (lane == 0) { red[wave][0] = acc0; red[wave][1] = acc1; }
    __syncthreads();
    if (t < 2) {
        float s = 0.f;
#pragma unroll
        for (int w = 0; w < NT / 64; ++w) s += red[w][t];
        table[p * 2 + t] = s;
    }
}

// out[b] = table[pattern(b)]
__global__ __launch_bounds__(256) void scatter_kernel(const float* __restrict__ x,
                                                      const float* __restrict__ table,
                                                      float2* __restrict__ out) {
    int b = blockIdx.x * 256 + threadIdx.x;
    if (b >= BATCH) return;
    float2 xv = *(const float2*)(x + (size_t)b * 2);
    int pat = (xv.x > 0.f ? 1 : 0) | (xv.y > 0.f ? 2 : 0);
    out[b] = ((const float2*)table)[pat];
}

extern "C" void kernel_launch(void* const* d_in, const int* in_sizes, int n_in,
                              void* d_out, int out_size, void* d_ws, size_t ws_size,
                              hipStream_t stream) {
    const float* x    = (const float*)d_in[0];
    const float* w0   = (const float*)d_in[1];
    const float* ws   = (const float*)d_in[2];
    const int*   idx0 = (const int*)d_in[3];
    const int*   idxs = (const int*)d_in[4];
    float*       out  = (float*)d_out;

    float4*   pcoef = (float4*)d_ws;                    // 384 KB
    unsigned* pidx  = (unsigned*)(pcoef + LTOT * KN);   //  96 KB
    float*    table = (float*)(pidx + LTOT * KN);       //  32 B

    pack_kernel<<<(LTOT * KN + 255) / 256, 256, 0, stream>>>(w0, ws, idx0, idxs, pidx, pcoef);
    net_kernel<<<NPAT, NT, 0, stream>>>(pidx, pcoef, table);
    scatter_kernel<<<(BATCH + 255) / 256, 256, 0, stream>>>(x, table, (float2*)out);
}